// Round 2
// baseline (451.820 us; speedup 1.0000x reference)
//
#include <hip/hip_runtime.h>
#include <stdint.h>

#define DIM   1024
#define L_SEQ 2048
#define BATCH 2
#define NH    8
#define M_TOT 4096   // BATCH * L_SEQ
#define EPS_F 1e-5f

typedef __bf16 bf16x8 __attribute__((ext_vector_type(8)));
typedef unsigned short u16x8 __attribute__((ext_vector_type(8)));
typedef float f32x4 __attribute__((ext_vector_type(4)));

__device__ __forceinline__ unsigned short f2bf(float f) {
  unsigned int u = __float_as_uint(f);
  u += 0x7FFFu + ((u >> 16) & 1u);   // RNE
  return (unsigned short)(u >> 16);
}

__device__ __forceinline__ f32x4 mfma_bf16(u16x8 a, u16x8 b, f32x4 c) {
  return __builtin_amdgcn_mfma_f32_16x16x32_bf16(
      __builtin_bit_cast(bf16x8, a), __builtin_bit_cast(bf16x8, b), c, 0, 0, 0);
}

__device__ __forceinline__ float silu_f(float v) {
  return v / (1.f + __expf(-v));
}

// ---------------- fp32 -> bf16 convert (vectorized) ----------------
__global__ __launch_bounds__(256) void cvt_bf16(const float4* __restrict__ src,
                                                ushort4* __restrict__ dst, int n4) {
  int i = blockIdx.x * 256 + threadIdx.x;
  if (i < n4) {
    float4 f = src[i];
    dst[i] = make_ushort4(f2bf(f.x), f2bf(f.y), f2bf(f.z), f2bf(f.w));
  }
}

// ---------------- ln_da = -exp(ln_a)*softplus(x . W_dt[h] + b_dt[h]) ----------------
// out layout: ln_da[(b*NH+h)*L_SEQ + l]
__global__ __launch_bounds__(256) void dt_kernel(const float* __restrict__ x,
                                                 const float* __restrict__ W_dt,
                                                 const float* __restrict__ b_dt,
                                                 const float* __restrict__ ln_a,
                                                 float* __restrict__ ln_da) {
  __shared__ float xs[DIM];
  const int row = blockIdx.x;                  // 0..4095
  const float* xr = x + (size_t)row * DIM;
  for (int i = threadIdx.x; i < DIM; i += 256) xs[i] = xr[i];
  __syncthreads();
  const int wave = threadIdx.x >> 6, lane = threadIdx.x & 63;
  for (int h = wave; h < NH; h += 4) {
    const float* w = W_dt + (size_t)h * DIM;
    float s = 0.f;
    for (int k = lane; k < DIM; k += 64) s += xs[k] * w[k];
    for (int off = 32; off > 0; off >>= 1) s += __shfl_down(s, off);
    if (lane == 0) {
      float t = s + b_dt[h];
      float sp = (t > 20.f) ? t : log1pf(expf(t));
      int b = row >> 11, l = row & (L_SEQ - 1);
      ln_da[(size_t)(b * NH + h) * L_SEQ + l] = -expf(ln_a[h]) * sp;
    }
  }
}

// ---------------- w[b,h,i] = z[b, m=h, h, i] in pure fp32 (the tril m==h diagonal term) ------
__global__ __launch_bounds__(256) void w_kernel(const float* __restrict__ x,
                                                const float* __restrict__ W_z,
                                                const float* __restrict__ W_za,
                                                const float* __restrict__ b_z,
                                                const float* __restrict__ b_za,
                                                float* __restrict__ w_out) {
  const int bh = blockIdx.x, b = bh >> 3, h = bh & 7;
  __shared__ float xs[DIM];
  const float* xr = x + (size_t)(b * L_SEQ + h) * DIM;   // sequence row m = h of batch b
  for (int i = threadIdx.x; i < DIM; i += 256) xs[i] = xr[i];
  __syncthreads();
  const int wave = threadIdx.x >> 6, lane = threadIdx.x & 63;
  for (int nl = wave; nl < 128; nl += 4) {
    const int n = h * 128 + nl;
    const float* wz = W_z + (size_t)n * DIM;
    const float* wa = W_za + (size_t)n * DIM;
    float su = 0.f, sv = 0.f;
    for (int k = lane; k < DIM; k += 64) { float xv = xs[k]; su += xv * wz[k]; sv += xv * wa[k]; }
    for (int off = 32; off > 0; off >>= 1) { su += __shfl_down(su, off); sv += __shfl_down(sv, off); }
    if (lane == 0) {
      float U = su + b_z[n], V = sv + b_za[n];
      w_out[(size_t)bh * 128 + nl] = U * (V / (1.f + expf(-V)));
    }
  }
}

// ---------------- fused dual GEMM: U=x@Wz^T, V=x@Wza^T; Zs += strict colsum((U+bz)*silu(V+bza)) ----
__global__ __launch_bounds__(256) void gemm_z(const unsigned short* __restrict__ xb,
                                              const unsigned short* __restrict__ Wz,
                                              const unsigned short* __restrict__ Wza,
                                              const float* __restrict__ b_z,
                                              const float* __restrict__ b_za,
                                              float* __restrict__ Zs) {
  __shared__ __align__(16) unsigned short As[128 * 32];
  __shared__ __align__(16) unsigned short Bz[128 * 32];
  __shared__ __align__(16) unsigned short Ba[128 * 32];
  __shared__ float colsum[128];

  const int tid = threadIdx.x;
  const int lane = tid & 63, wave = tid >> 6;
  const int wm = wave >> 1, wn = wave & 1;
  const int l16 = lane & 15, quad = lane >> 4;
  const int nt = blockIdx.x, mt = blockIdx.y;
  const int m0 = mt * 128, n0 = nt * 128;

  const int rr = tid >> 2;   // staging row 0..63
  const int kc = tid & 3;    // k-chunk 0..3

  const unsigned short* gA0 = xb  + (size_t)(m0 + rr) * DIM + kc * 8;
  const unsigned short* gA1 = gA0 + (size_t)64 * DIM;
  const unsigned short* gZ0 = Wz  + (size_t)(n0 + rr) * DIM + kc * 8;
  const unsigned short* gZ1 = gZ0 + (size_t)64 * DIM;
  const unsigned short* gB0 = Wza + (size_t)(n0 + rr) * DIM + kc * 8;
  const unsigned short* gB1 = gB0 + (size_t)64 * DIM;

  u16x8* Asv = (u16x8*)As;
  u16x8* Bzv = (u16x8*)Bz;
  u16x8* Bav = (u16x8*)Ba;

  f32x4 accZ[4][4], accA[4][4];
  const f32x4 zero = {0.f, 0.f, 0.f, 0.f};
  for (int i = 0; i < 4; ++i)
    for (int j = 0; j < 4; ++j) { accZ[i][j] = zero; accA[i][j] = zero; }

  for (int kt = 0; kt < 32; ++kt) {
    u16x8 a0 = *(const u16x8*)gA0;  gA0 += 32;
    u16x8 a1 = *(const u16x8*)gA1;  gA1 += 32;
    u16x8 z0 = *(const u16x8*)gZ0;  gZ0 += 32;
    u16x8 z1 = *(const u16x8*)gZ1;  gZ1 += 32;
    u16x8 c0 = *(const u16x8*)gB0;  gB0 += 32;
    u16x8 c1 = *(const u16x8*)gB1;  gB1 += 32;
    __syncthreads();
    Asv[tid] = a0; Asv[tid + 256] = a1;
    Bzv[tid] = z0; Bzv[tid + 256] = z1;
    Bav[tid] = c0; Bav[tid + 256] = c1;
    __syncthreads();

    u16x8 aF[4], bFz[4], bFa[4];
#pragma unroll
    for (int rb = 0; rb < 4; ++rb)
      aF[rb] = *(const u16x8*)&As[(wm * 64 + rb * 16 + l16) * 32 + quad * 8];
#pragma unroll
    for (int cb = 0; cb < 4; ++cb) {
      bFz[cb] = *(const u16x8*)&Bz[(wn * 64 + cb * 16 + l16) * 32 + quad * 8];
      bFa[cb] = *(const u16x8*)&Ba[(wn * 64 + cb * 16 + l16) * 32 + quad * 8];
    }
#pragma unroll
    for (int rb = 0; rb < 4; ++rb)
#pragma unroll
      for (int cb = 0; cb < 4; ++cb) {
        accZ[rb][cb] = mfma_bf16(aF[rb], bFz[cb], accZ[rb][cb]);
        accA[rb][cb] = mfma_bf16(aF[rb], bFa[cb], accA[rb][cb]);
      }
  }

  __syncthreads();
  if (tid < 128) colsum[tid] = 0.f;
  __syncthreads();

  const int b = m0 >> 11;
#pragma unroll
  for (int cb = 0; cb < 4; ++cb) {
    const int nl = wn * 64 + cb * 16 + l16;
    const int n = n0 + nl;
    const int h = n >> 7;
    const float bz = b_z[n], ba = b_za[n];
    float s = 0.f;
#pragma unroll
    for (int rb = 0; rb < 4; ++rb) {
      const int mlb = wm * 64 + rb * 16 + quad * 4;
#pragma unroll
      for (int r = 0; r < 4; ++r) {
        const int l = (m0 + mlb + r) & (L_SEQ - 1);
        float u  = accZ[rb][cb][r] + bz;
        float vv = accA[rb][cb][r] + ba;
        if (l > h) s += u * silu_f(vv);   // strict: m >= h+1 only (m==h handled by w_kernel)
      }
    }
    atomicAdd(&colsum[nl], s);
  }
  __syncthreads();
  if (tid < 128) atomicAdd(&Zs[(size_t)b * DIM + n0 + tid], colsum[tid]);
}

// ---- per (b,h): v = Zs+hidden; stats (svv, svw, sww); Gv = (v-μv)·gnw·Wy, Gw = (w-μw)·gnw·Wy ----
__global__ __launch_bounds__(256) void prep_kernel(const float* __restrict__ Zs,
                                                   const float* __restrict__ hidden,
                                                   const float* __restrict__ w_in,
                                                   const float* __restrict__ gn_w,
                                                   const float* __restrict__ W_y,
                                                   float* __restrict__ v_out,
                                                   float* __restrict__ stats3,
                                                   float* __restrict__ Gv,
                                                   float* __restrict__ Gw) {
  const int bh = blockIdx.x, b = bh >> 3, h = bh & 7;
  const int tid = threadIdx.x;
  __shared__ float vsh[128], wsh[128], vt[128], wt[128], mu[2];
  if (tid < 128) {
    float v = Zs[(size_t)b * DIM + h * 128 + tid] + hidden[(size_t)bh * 128 + tid];
    float w = w_in[(size_t)bh * 128 + tid];
    vsh[tid] = v; wsh[tid] = w;
    v_out[(size_t)bh * 128 + tid] = v;
  }
  __syncthreads();
  if (tid == 0) {
    float sv = 0.f, sw = 0.f;
    for (int i = 0; i < 128; ++i) { sv += vsh[i]; sw += wsh[i]; }
    mu[0] = sv * (1.f / 128.f); mu[1] = sw * (1.f / 128.f);
  }
  __syncthreads();
  const float muv = mu[0], muw = mu[1];
  if (tid < 128) { vt[tid] = vsh[tid] - muv; wt[tid] = wsh[tid] - muw; }
  __syncthreads();
  if (tid == 0) {
    float svv = 0.f, svw = 0.f, sww = 0.f;
    for (int i = 0; i < 128; ++i) {
      float a = vt[i], c = wt[i];
      svv += a * a; svw += a * c; sww += c * c;
    }
    stats3[bh * 3 + 0] = svv * (1.f / 128.f);
    stats3[bh * 3 + 1] = svw * (1.f / 128.f);
    stats3[bh * 3 + 2] = sww * (1.f / 128.f);
  }
  __syncthreads();
  const float gw = gn_w[h];
  for (int n = tid; n < DIM; n += 256) {
    const float* wr = W_y + (size_t)n * DIM + h * 128;
    float sv = 0.f, sw = 0.f;
#pragma unroll 4
    for (int i = 0; i < 128; ++i) { float wy = wr[i]; sv += vt[i] * wy; sw += wt[i] * wy; }
    Gv[(size_t)bh * DIM + n] = sv * gw;
    Gw[(size_t)bh * DIM + n] = sw * gw;
  }
}

// ---------------- const_c[n] = b_y[n] + sum_h gn_b[h] * sum_i W_y[n, h*128+i] ----------------
__global__ __launch_bounds__(256) void constc_kernel(const float* __restrict__ W_y,
                                                     const float* __restrict__ gn_b,
                                                     const float* __restrict__ b_y,
                                                     float* __restrict__ constc) {
  const int n = blockIdx.x * 256 + threadIdx.x;  // grid 4 -> 1024
  const float* wr = W_y + (size_t)n * DIM;
  float s = b_y[n];
  for (int h = 0; h < NH; ++h) {
    float t = 0.f;
#pragma unroll 4
    for (int i = 0; i < 128; ++i) t += wr[h * 128 + i];
    s += gn_b[h] * t;
  }
  constc[n] = s;
}

// ---- scan: S=cumsum(ln_da); c=exp(S); D=rsqrt(c^2*svv+2c*svw+sww+eps); alpha2=(c*D, D) ----
__global__ __launch_bounds__(64) void scan_kernel(const float* __restrict__ ln_da,
                                                  const float* __restrict__ stats3,
                                                  const float* __restrict__ v,
                                                  const float* __restrict__ w_in,
                                                  float* __restrict__ alpha2,
                                                  float* __restrict__ hidden_next) {
  const int bh = blockIdx.x, b = bh >> 3, h = bh & 7;
  const int lane = threadIdx.x;
  const float* src = ln_da + (size_t)bh * L_SEQ;
  const float svv = stats3[bh * 3 + 0];
  const float svw = stats3[bh * 3 + 1];
  const float sww = stats3[bh * 3 + 2];
  float carry = 0.f;
  for (int c = 0; c < L_SEQ / 64; ++c) {
    float val = src[c * 64 + lane];
#pragma unroll
    for (int off = 1; off < 64; off <<= 1) {
      float nv = __shfl_up(val, off);
      if (lane >= off) val += nv;
    }
    const float S = carry + val;
    const float ce = expf(S);
    const float D = rsqrtf(ce * ce * svv + 2.f * ce * svw + sww + EPS_F);
    const int l = c * 64 + lane;
    float* ap = alpha2 + ((size_t)(b * L_SEQ + l) * NH + h) * 2;
    ap[0] = ce * D;
    ap[1] = D;
    carry += __shfl(val, 63);
  }
  const float clast = expf(carry);
  for (int i = lane; i < 128; i += 64)
    hidden_next[(size_t)bh * 128 + i] =
        clast * v[(size_t)bh * 128 + i] + w_in[(size_t)bh * 128 + i];
}

// ---------------- GEMM y: C=x@Wya^T; y = (Σ_h αv·Gv + αw·Gw + const) * silu(C + b_ya) ----------
__global__ __launch_bounds__(256) void gemm_y(const unsigned short* __restrict__ xb,
                                              const unsigned short* __restrict__ Wya,
                                              const float* __restrict__ b_ya,
                                              const float* __restrict__ alpha2,
                                              const float* __restrict__ Gv,
                                              const float* __restrict__ Gw,
                                              const float* __restrict__ constc,
                                              float* __restrict__ y) {
  __shared__ __align__(16) unsigned short As[128 * 32];
  __shared__ __align__(16) unsigned short Bs[128 * 32];
  __shared__ float alphaS[128 * 16];
  __shared__ float gS[16 * 128];
  __shared__ float cS[128];
  __shared__ float bS[128];

  const int tid = threadIdx.x;
  const int lane = tid & 63, wave = tid >> 6;
  const int wm = wave >> 1, wn = wave & 1;
  const int l16 = lane & 15, quad = lane >> 4;
  const int nt = blockIdx.x, mt = blockIdx.y;
  const int m0 = mt * 128, n0 = nt * 128;

  const int rr = tid >> 2;
  const int kc = tid & 3;

  const unsigned short* gA0 = xb  + (size_t)(m0 + rr) * DIM + kc * 8;
  const unsigned short* gA1 = gA0 + (size_t)64 * DIM;
  const unsigned short* gB0 = Wya + (size_t)(n0 + rr) * DIM + kc * 8;
  const unsigned short* gB1 = gB0 + (size_t)64 * DIM;

  u16x8* Asv = (u16x8*)As;
  u16x8* Bsv = (u16x8*)Bs;

  f32x4 acc[4][4];
  const f32x4 zero = {0.f, 0.f, 0.f, 0.f};
  for (int i = 0; i < 4; ++i)
    for (int j = 0; j < 4; ++j) acc[i][j] = zero;

  for (int kt = 0; kt < 32; ++kt) {
    u16x8 a0 = *(const u16x8*)gA0;  gA0 += 32;
    u16x8 a1 = *(const u16x8*)gA1;  gA1 += 32;
    u16x8 c0 = *(const u16x8*)gB0;  gB0 += 32;
    u16x8 c1 = *(const u16x8*)gB1;  gB1 += 32;
    __syncthreads();
    Asv[tid] = a0; Asv[tid + 256] = a1;
    Bsv[tid] = c0; Bsv[tid + 256] = c1;
    __syncthreads();

    u16x8 aF[4], bF[4];
#pragma unroll
    for (int rb = 0; rb < 4; ++rb)
      aF[rb] = *(const u16x8*)&As[(wm * 64 + rb * 16 + l16) * 32 + quad * 8];
#pragma unroll
    for (int cb = 0; cb < 4; ++cb)
      bF[cb] = *(const u16x8*)&Bs[(wn * 64 + cb * 16 + l16) * 32 + quad * 8];
#pragma unroll
    for (int rb = 0; rb < 4; ++rb)
#pragma unroll
      for (int cb = 0; cb < 4; ++cb)
        acc[rb][cb] = mfma_bf16(aF[rb], bF[cb], acc[rb][cb]);
  }

  __syncthreads();
  {
    const int b = m0 >> 11;
    const float* ap = alpha2 + (size_t)m0 * NH * 2;
    for (int i = tid; i < 128 * 16; i += 256) alphaS[i] = ap[i];
    for (int i = tid; i < 16 * 128; i += 256) {
      int h2 = i >> 7, n = i & 127, h = h2 >> 1;
      const float* src = (h2 & 1) ? Gw : Gv;
      gS[i] = src[(size_t)(b * NH + h) * DIM + n0 + n];
    }
    if (tid < 128) { cS[tid] = constc[n0 + tid]; bS[tid] = b_ya[n0 + tid]; }
  }
  __syncthreads();

#pragma unroll
  for (int rb = 0; rb < 4; ++rb)
#pragma unroll
    for (int cb = 0; cb < 4; ++cb) {
      const int nl = wn * 64 + cb * 16 + l16;
#pragma unroll
      for (int r = 0; r < 4; ++r) {
        const int ml = wm * 64 + rb * 16 + quad * 4 + r;
        float Ay = cS[nl];
        const float* ar = &alphaS[ml * 16];
#pragma unroll
        for (int h = 0; h < NH; ++h)
          Ay += ar[2 * h] * gS[(2 * h) * 128 + nl] + ar[2 * h + 1] * gS[(2 * h + 1) * 128 + nl];
        const float sv = silu_f(acc[rb][cb][r] + bS[nl]);
        y[(size_t)(m0 + ml) * DIM + n0 + nl] = Ay * sv;
      }
    }
}

extern "C" void kernel_launch(void* const* d_in, const int* in_sizes, int n_in,
                              void* d_out, int out_size, void* d_ws, size_t ws_size,
                              hipStream_t stream) {
  const float* x      = (const float*)d_in[0];
  const float* hidden = (const float*)d_in[1];
  const float* W_z    = (const float*)d_in[2];
  const float* b_z    = (const float*)d_in[3];
  const float* W_za   = (const float*)d_in[4];
  const float* b_za   = (const float*)d_in[5];
  const float* W_y    = (const float*)d_in[6];
  const float* b_y    = (const float*)d_in[7];
  const float* W_ya   = (const float*)d_in[8];
  const float* b_ya   = (const float*)d_in[9];
  const float* W_dt   = (const float*)d_in[10];
  const float* b_dt   = (const float*)d_in[11];
  const float* ln_a   = (const float*)d_in[12];
  const float* gn_w   = (const float*)d_in[13];
  const float* gn_b   = (const float*)d_in[14];

  char* ws = (char*)d_ws;
  unsigned short* xb   = (unsigned short*)(ws);             // 8,388,608 B
  unsigned short* Wzb  = (unsigned short*)(ws + 8388608);   // 2,097,152 B
  unsigned short* Wzab = (unsigned short*)(ws + 10485760);  // 2,097,152 B
  unsigned short* Wyab = (unsigned short*)(ws + 12582912);  // 2,097,152 B
  float* ln_da  = (float*)(ws + 14680064);                  // 131,072 B
  float* Zs     = (float*)(ws + 14811136);                  // 8,192 B
  float* v      = (float*)(ws + 14819328);                  // 8,192 B
  float* wdiag  = (float*)(ws + 14827520);                  // 8,192 B
  float* stats3 = (float*)(ws + 14835712);                  // 256 B
  float* Gv     = (float*)(ws + 14835968);                  // 65,536 B
  float* Gw     = (float*)(ws + 14901504);                  // 65,536 B
  float* constc = (float*)(ws + 14967040);                  // 4,096 B
  float* alpha2 = (float*)(ws + 14971136);                  // 262,144 B

  float* y = (float*)d_out;
  float* hidden_next = y + (size_t)M_TOT * DIM;

  hipMemsetAsync(Zs, 0, BATCH * DIM * sizeof(float), stream);

  cvt_bf16<<<4096, 256, 0, stream>>>((const float4*)x,    (ushort4*)xb,   1048576);
  cvt_bf16<<<1024, 256, 0, stream>>>((const float4*)W_z,  (ushort4*)Wzb,  262144);
  cvt_bf16<<<1024, 256, 0, stream>>>((const float4*)W_za, (ushort4*)Wzab, 262144);
  cvt_bf16<<<1024, 256, 0, stream>>>((const float4*)W_ya, (ushort4*)Wyab, 262144);

  dt_kernel<<<M_TOT, 256, 0, stream>>>(x, W_dt, b_dt, ln_a, ln_da);
  w_kernel<<<16, 256, 0, stream>>>(x, W_z, W_za, b_z, b_za, wdiag);

  gemm_z<<<dim3(8, 32), 256, 0, stream>>>(xb, Wzb, Wzab, b_z, b_za, Zs);

  prep_kernel<<<16, 256, 0, stream>>>(Zs, hidden, wdiag, gn_w, W_y, v, stats3, Gv, Gw);
  constc_kernel<<<4, 256, 0, stream>>>(W_y, gn_b, b_y, constc);
  scan_kernel<<<16, 64, 0, stream>>>(ln_da, stats3, v, wdiag, alpha2, hidden_next);

  gemm_y<<<dim3(8, 32), 256, 0, stream>>>(xb, Wyab, b_ya, alpha2, Gv, Gw, constc, y);
}

// Round 3
// 225.062 us; speedup vs baseline: 2.0075x; 2.0075x over previous
//
#include <hip/hip_runtime.h>
#include <stdint.h>

#define DIM   1024
#define L_SEQ 2048
#define BATCH 2
#define NH    8
#define M_TOT 4096   // BATCH * L_SEQ
#define EPS_F 1e-5f

typedef __bf16 bf16x8 __attribute__((ext_vector_type(8)));
typedef unsigned short u16x8 __attribute__((ext_vector_type(8)));
typedef float f32x4 __attribute__((ext_vector_type(4)));

__device__ __forceinline__ unsigned short f2bf(float f) {
  unsigned int u = __float_as_uint(f);
  u += 0x7FFFu + ((u >> 16) & 1u);   // RNE
  return (unsigned short)(u >> 16);
}

__device__ __forceinline__ f32x4 mfma_bf16(u16x8 a, u16x8 b, f32x4 c) {
  return __builtin_amdgcn_mfma_f32_16x16x32_bf16(
      __builtin_bit_cast(bf16x8, a), __builtin_bit_cast(bf16x8, b), c, 0, 0, 0);
}

__device__ __forceinline__ float silu_f(float v) {
  return v / (1.f + __expf(-v));
}

// ---------------- fp32 -> bf16 convert, all four tensors in one launch ----------------
__global__ __launch_bounds__(256) void cvt_all(const float4* __restrict__ x,
                                               const float4* __restrict__ wz,
                                               const float4* __restrict__ wza,
                                               const float4* __restrict__ wya,
                                               ushort4* __restrict__ xb,
                                               ushort4* __restrict__ wzb,
                                               ushort4* __restrict__ wzab,
                                               ushort4* __restrict__ wyab) {
  int i = blockIdx.x * 256 + threadIdx.x;   // grid covers 1835008 float4s
  const float4* s; ushort4* d; int j;
  if (i < 1048576)      { s = x;   d = xb;   j = i; }
  else if (i < 1310720) { s = wz;  d = wzb;  j = i - 1048576; }
  else if (i < 1572864) { s = wza; d = wzab; j = i - 1310720; }
  else                  { s = wya; d = wyab; j = i - 1572864; }
  float4 f = s[j];
  d[j] = make_ushort4(f2bf(f.x), f2bf(f.y), f2bf(f.z), f2bf(f.w));
}

// ---------------- ln_da = -exp(ln_a)*softplus(x . W_dt[h] + b_dt[h]) ----------------
// out layout: ln_da[(b*NH+h)*L_SEQ + l]
__global__ __launch_bounds__(256) void dt_kernel(const float* __restrict__ x,
                                                 const float* __restrict__ W_dt,
                                                 const float* __restrict__ b_dt,
                                                 const float* __restrict__ ln_a,
                                                 float* __restrict__ ln_da) {
  __shared__ float xs[DIM];
  const int row = blockIdx.x;                  // 0..4095
  const float* xr = x + (size_t)row * DIM;
  for (int i = threadIdx.x; i < DIM; i += 256) xs[i] = xr[i];
  __syncthreads();
  const int wave = threadIdx.x >> 6, lane = threadIdx.x & 63;
  for (int h = wave; h < NH; h += 4) {
    const float* w = W_dt + (size_t)h * DIM;
    float s = 0.f;
    for (int k = lane; k < DIM; k += 64) s += xs[k] * w[k];
    for (int off = 32; off > 0; off >>= 1) s += __shfl_down(s, off);
    if (lane == 0) {
      float t = s + b_dt[h];
      float sp = (t > 20.f) ? t : log1pf(expf(t));
      int b = row >> 11, l = row & (L_SEQ - 1);
      ln_da[(size_t)(b * NH + h) * L_SEQ + l] = -expf(ln_a[h]) * sp;
    }
  }
}

// ---- fused dual GEMM: U=x@Wz^T, V=x@Wza^T; Zs += strict colsum; wdiag = diagonal (l==h) ----
__global__ __launch_bounds__(256) void gemm_z(const unsigned short* __restrict__ xb,
                                              const unsigned short* __restrict__ Wz,
                                              const unsigned short* __restrict__ Wza,
                                              const float* __restrict__ b_z,
                                              const float* __restrict__ b_za,
                                              float* __restrict__ Zs,
                                              float* __restrict__ wdiag) {
  __shared__ __align__(16) unsigned short As[128 * 32];
  __shared__ __align__(16) unsigned short Bz[128 * 32];
  __shared__ __align__(16) unsigned short Ba[128 * 32];
  __shared__ float colsum[128];

  const int tid = threadIdx.x;
  const int lane = tid & 63, wave = tid >> 6;
  const int wm = wave >> 1, wn = wave & 1;
  const int l16 = lane & 15, quad = lane >> 4;
  const int nt = blockIdx.x, mt = blockIdx.y;
  const int m0 = mt * 128, n0 = nt * 128;

  const int rr = tid >> 2;   // staging row 0..63
  const int kc = tid & 3;    // k-chunk 0..3

  const unsigned short* gA0 = xb  + (size_t)(m0 + rr) * DIM + kc * 8;
  const unsigned short* gA1 = gA0 + (size_t)64 * DIM;
  const unsigned short* gZ0 = Wz  + (size_t)(n0 + rr) * DIM + kc * 8;
  const unsigned short* gZ1 = gZ0 + (size_t)64 * DIM;
  const unsigned short* gB0 = Wza + (size_t)(n0 + rr) * DIM + kc * 8;
  const unsigned short* gB1 = gB0 + (size_t)64 * DIM;

  u16x8* Asv = (u16x8*)As;
  u16x8* Bzv = (u16x8*)Bz;
  u16x8* Bav = (u16x8*)Ba;

  f32x4 accZ[4][4], accA[4][4];
  const f32x4 zero = {0.f, 0.f, 0.f, 0.f};
  for (int i = 0; i < 4; ++i)
    for (int j = 0; j < 4; ++j) { accZ[i][j] = zero; accA[i][j] = zero; }

  for (int kt = 0; kt < 32; ++kt) {
    u16x8 a0 = *(const u16x8*)gA0;  gA0 += 32;
    u16x8 a1 = *(const u16x8*)gA1;  gA1 += 32;
    u16x8 z0 = *(const u16x8*)gZ0;  gZ0 += 32;
    u16x8 z1 = *(const u16x8*)gZ1;  gZ1 += 32;
    u16x8 c0 = *(const u16x8*)gB0;  gB0 += 32;
    u16x8 c1 = *(const u16x8*)gB1;  gB1 += 32;
    __syncthreads();
    Asv[tid] = a0; Asv[tid + 256] = a1;
    Bzv[tid] = z0; Bzv[tid + 256] = z1;
    Bav[tid] = c0; Bav[tid + 256] = c1;
    __syncthreads();

    u16x8 aF[4], bFz[4], bFa[4];
#pragma unroll
    for (int rb = 0; rb < 4; ++rb)
      aF[rb] = *(const u16x8*)&As[(wm * 64 + rb * 16 + l16) * 32 + quad * 8];
#pragma unroll
    for (int cb = 0; cb < 4; ++cb) {
      bFz[cb] = *(const u16x8*)&Bz[(wn * 64 + cb * 16 + l16) * 32 + quad * 8];
      bFa[cb] = *(const u16x8*)&Ba[(wn * 64 + cb * 16 + l16) * 32 + quad * 8];
    }
#pragma unroll
    for (int rb = 0; rb < 4; ++rb)
#pragma unroll
      for (int cb = 0; cb < 4; ++cb) {
        accZ[rb][cb] = mfma_bf16(aF[rb], bFz[cb], accZ[rb][cb]);
        accA[rb][cb] = mfma_bf16(aF[rb], bFa[cb], accA[rb][cb]);
      }
  }

  __syncthreads();
  if (tid < 128) colsum[tid] = 0.f;
  __syncthreads();

  const int b = m0 >> 11;
#pragma unroll
  for (int cb = 0; cb < 4; ++cb) {
    const int nl = wn * 64 + cb * 16 + l16;
    const int n = n0 + nl;
    const int h = n >> 7;     // == nt
    const float bz = b_z[n], ba = b_za[n];
    float s = 0.f;
#pragma unroll
    for (int rb = 0; rb < 4; ++rb) {
      const int mlb = wm * 64 + rb * 16 + quad * 4;
#pragma unroll
      for (int r = 0; r < 4; ++r) {
        const int l = (m0 + mlb + r) & (L_SEQ - 1);
        float u  = accZ[rb][cb][r] + bz;
        float vv = accA[rb][cb][r] + ba;
        if (l > h) s += u * silu_f(vv);            // strict lower part -> colsum
        else if (l == h)                            // diagonal term -> wdiag[b,h,i]
          wdiag[(size_t)(b * NH + h) * 128 + nl] = u * silu_f(vv);
      }
    }
    atomicAdd(&colsum[nl], s);
  }
  __syncthreads();
  if (tid < 128) atomicAdd(&Zs[(size_t)b * DIM + n0 + tid], colsum[tid]);
}

// ---- per (b,h): v = Zs+hidden; centered vt,wt; stats (svv,svw,sww); vtg=vt*gnw, wtg=wt*gnw ----
__global__ __launch_bounds__(64) void stats_kernel(const float* __restrict__ Zs,
                                                   const float* __restrict__ hidden,
                                                   const float* __restrict__ wdiag,
                                                   const float* __restrict__ gn_w,
                                                   float* __restrict__ v_out,
                                                   float* __restrict__ vtg,
                                                   float* __restrict__ wtg,
                                                   float* __restrict__ stats3) {
  const int bh = blockIdx.x, b = bh >> 3, h = bh & 7;
  const int lane = threadIdx.x;
  const size_t base = (size_t)bh * 128;
  float v0 = Zs[(size_t)b * DIM + h * 128 + lane]      + hidden[base + lane];
  float v1 = Zs[(size_t)b * DIM + h * 128 + 64 + lane] + hidden[base + 64 + lane];
  float w0 = wdiag[base + lane];
  float w1 = wdiag[base + 64 + lane];
  v_out[base + lane] = v0;
  v_out[base + 64 + lane] = v1;

  float sv = v0 + v1, sw = w0 + w1;
  for (int off = 32; off > 0; off >>= 1) {
    sv += __shfl_down(sv, off);
    sw += __shfl_down(sw, off);
  }
  const float muv = __shfl(sv, 0) * (1.f / 128.f);
  const float muw = __shfl(sw, 0) * (1.f / 128.f);

  const float a0 = v0 - muv, a1 = v1 - muv;
  const float c0 = w0 - muw, c1 = w1 - muw;
  float svv = a0 * a0 + a1 * a1;
  float svw = a0 * c0 + a1 * c1;
  float sww = c0 * c0 + c1 * c1;
  for (int off = 32; off > 0; off >>= 1) {
    svv += __shfl_down(svv, off);
    svw += __shfl_down(svw, off);
    sww += __shfl_down(sww, off);
  }
  if (lane == 0) {
    stats3[bh * 3 + 0] = svv * (1.f / 128.f);
    stats3[bh * 3 + 1] = svw * (1.f / 128.f);
    stats3[bh * 3 + 2] = sww * (1.f / 128.f);
  }
  const float gw = gn_w[h];
  vtg[base + lane] = a0 * gw;  vtg[base + 64 + lane] = a1 * gw;
  wtg[base + lane] = c0 * gw;  wtg[base + 64 + lane] = c1 * gw;
}

// ---- per row n of W_y: Gv[bh][n], Gw[bh][n] (all 16 bh) and constc[n] ----
// grid 256 x 256thr; wave = one row n. Row read coalesced float4.
__global__ __launch_bounds__(256) void proj_kernel(const float* __restrict__ W_y,
                                                   const float* __restrict__ vtg,
                                                   const float* __restrict__ wtg,
                                                   const float* __restrict__ gn_b,
                                                   const float* __restrict__ b_y,
                                                   float* __restrict__ Gv,
                                                   float* __restrict__ Gw,
                                                   float* __restrict__ constc) {
  const int tid = threadIdx.x, wave = tid >> 6, lane = tid & 63;
  const int n = blockIdx.x * 4 + wave;
  const float4* row = (const float4*)(W_y + (size_t)n * DIM);
  const int half = lane >> 5, l32 = lane & 31;
  float cc = 0.f;
#pragma unroll
  for (int p = 0; p < 4; ++p) {
    const int h = p * 2 + half;          // head covered by this half-wave in pass p
    float4 wv = row[p * 64 + lane];      // elements k..k+3, k = p*256+lane*4
    const float4 va = *(const float4*)&vtg[(size_t)h * 128 + l32 * 4];          // b=0
    const float4 vb = *(const float4*)&vtg[(size_t)(8 + h) * 128 + l32 * 4];    // b=1
    const float4 wa = *(const float4*)&wtg[(size_t)h * 128 + l32 * 4];
    const float4 wb = *(const float4*)&wtg[(size_t)(8 + h) * 128 + l32 * 4];
    float gv0 = wv.x * va.x + wv.y * va.y + wv.z * va.z + wv.w * va.w;
    float gv1 = wv.x * vb.x + wv.y * vb.y + wv.z * vb.z + wv.w * vb.w;
    float gw0 = wv.x * wa.x + wv.y * wa.y + wv.z * wa.z + wv.w * wa.w;
    float gw1 = wv.x * wb.x + wv.y * wb.y + wv.z * wb.z + wv.w * wb.w;
    cc += (wv.x + wv.y + wv.z + wv.w) * gn_b[h];
#pragma unroll
    for (int off = 16; off > 0; off >>= 1) {
      gv0 += __shfl_down(gv0, off, 32);
      gv1 += __shfl_down(gv1, off, 32);
      gw0 += __shfl_down(gw0, off, 32);
      gw1 += __shfl_down(gw1, off, 32);
    }
    if (l32 == 0) {
      Gv[(size_t)h * DIM + n]       = gv0;
      Gv[(size_t)(8 + h) * DIM + n] = gv1;
      Gw[(size_t)h * DIM + n]       = gw0;
      Gw[(size_t)(8 + h) * DIM + n] = gw1;
    }
  }
  for (int off = 32; off > 0; off >>= 1) cc += __shfl_down(cc, off);
  if (lane == 0) constc[n] = b_y[n] + cc;
}

// ---- scan: S=cumsum(ln_da); c=exp(S); D=rsqrt(c^2*svv+2c*svw+sww+eps); alpha2=(c*D, D) ----
__global__ __launch_bounds__(64) void scan_kernel(const float* __restrict__ ln_da,
                                                  const float* __restrict__ stats3,
                                                  const float* __restrict__ v,
                                                  const float* __restrict__ w_in,
                                                  float* __restrict__ alpha2,
                                                  float* __restrict__ hidden_next) {
  const int bh = blockIdx.x, b = bh >> 3, h = bh & 7;
  const int lane = threadIdx.x;
  const float* src = ln_da + (size_t)bh * L_SEQ;
  const float svv = stats3[bh * 3 + 0];
  const float svw = stats3[bh * 3 + 1];
  const float sww = stats3[bh * 3 + 2];
  float carry = 0.f;
  for (int c = 0; c < L_SEQ / 64; ++c) {
    float val = src[c * 64 + lane];
#pragma unroll
    for (int off = 1; off < 64; off <<= 1) {
      float nv = __shfl_up(val, off);
      if (lane >= off) val += nv;
    }
    const float S = carry + val;
    const float ce = expf(S);
    const float D = rsqrtf(ce * ce * svv + 2.f * ce * svw + sww + EPS_F);
    const int l = c * 64 + lane;
    float* ap = alpha2 + ((size_t)(b * L_SEQ + l) * NH + h) * 2;
    ap[0] = ce * D;
    ap[1] = D;
    carry += __shfl(val, 63);
  }
  const float clast = expf(carry);
  for (int i = lane; i < 128; i += 64)
    hidden_next[(size_t)bh * 128 + i] =
        clast * v[(size_t)bh * 128 + i] + w_in[(size_t)bh * 128 + i];
}

// ---------------- GEMM y: C=x@Wya^T; y = (Σ_h αv·Gv + αw·Gw + const) * silu(C + b_ya) ----------
__global__ __launch_bounds__(256) void gemm_y(const unsigned short* __restrict__ xb,
                                              const unsigned short* __restrict__ Wya,
                                              const float* __restrict__ b_ya,
                                              const float* __restrict__ alpha2,
                                              const float* __restrict__ Gv,
                                              const float* __restrict__ Gw,
                                              const float* __restrict__ constc,
                                              float* __restrict__ y) {
  __shared__ __align__(16) unsigned short As[128 * 32];
  __shared__ __align__(16) unsigned short Bs[128 * 32];
  __shared__ float alphaS[128 * 16];
  __shared__ float gS[16 * 128];
  __shared__ float cS[128];
  __shared__ float bS[128];

  const int tid = threadIdx.x;
  const int lane = tid & 63, wave = tid >> 6;
  const int wm = wave >> 1, wn = wave & 1;
  const int l16 = lane & 15, quad = lane >> 4;
  const int nt = blockIdx.x, mt = blockIdx.y;
  const int m0 = mt * 128, n0 = nt * 128;

  const int rr = tid >> 2;
  const int kc = tid & 3;

  const unsigned short* gA0 = xb  + (size_t)(m0 + rr) * DIM + kc * 8;
  const unsigned short* gA1 = gA0 + (size_t)64 * DIM;
  const unsigned short* gB0 = Wya + (size_t)(n0 + rr) * DIM + kc * 8;
  const unsigned short* gB1 = gB0 + (size_t)64 * DIM;

  u16x8* Asv = (u16x8*)As;
  u16x8* Bsv = (u16x8*)Bs;

  f32x4 acc[4][4];
  const f32x4 zero = {0.f, 0.f, 0.f, 0.f};
  for (int i = 0; i < 4; ++i)
    for (int j = 0; j < 4; ++j) acc[i][j] = zero;

  for (int kt = 0; kt < 32; ++kt) {
    u16x8 a0 = *(const u16x8*)gA0;  gA0 += 32;
    u16x8 a1 = *(const u16x8*)gA1;  gA1 += 32;
    u16x8 c0 = *(const u16x8*)gB0;  gB0 += 32;
    u16x8 c1 = *(const u16x8*)gB1;  gB1 += 32;
    __syncthreads();
    Asv[tid] = a0; Asv[tid + 256] = a1;
    Bsv[tid] = c0; Bsv[tid + 256] = c1;
    __syncthreads();

    u16x8 aF[4], bF[4];
#pragma unroll
    for (int rb = 0; rb < 4; ++rb)
      aF[rb] = *(const u16x8*)&As[(wm * 64 + rb * 16 + l16) * 32 + quad * 8];
#pragma unroll
    for (int cb = 0; cb < 4; ++cb)
      bF[cb] = *(const u16x8*)&Bs[(wn * 64 + cb * 16 + l16) * 32 + quad * 8];
#pragma unroll
    for (int rb = 0; rb < 4; ++rb)
#pragma unroll
      for (int cb = 0; cb < 4; ++cb)
        acc[rb][cb] = mfma_bf16(aF[rb], bF[cb], acc[rb][cb]);
  }

  __syncthreads();
  {
    const int b = m0 >> 11;
    const float* ap = alpha2 + (size_t)m0 * NH * 2;
    for (int i = tid; i < 128 * 16; i += 256) alphaS[i] = ap[i];
    for (int i = tid; i < 16 * 128; i += 256) {
      int h2 = i >> 7, n = i & 127, h = h2 >> 1;
      const float* src = (h2 & 1) ? Gw : Gv;
      gS[i] = src[(size_t)(b * NH + h) * DIM + n0 + n];
    }
    if (tid < 128) { cS[tid] = constc[n0 + tid]; bS[tid] = b_ya[n0 + tid]; }
  }
  __syncthreads();

#pragma unroll
  for (int rb = 0; rb < 4; ++rb)
#pragma unroll
    for (int cb = 0; cb < 4; ++cb) {
      const int nl = wn * 64 + cb * 16 + l16;
#pragma unroll
      for (int r = 0; r < 4; ++r) {
        const int ml = wm * 64 + rb * 16 + quad * 4 + r;
        float Ay = cS[nl];
        const float* ar = &alphaS[ml * 16];
#pragma unroll
        for (int h = 0; h < NH; ++h)
          Ay += ar[2 * h] * gS[(2 * h) * 128 + nl] + ar[2 * h + 1] * gS[(2 * h + 1) * 128 + nl];
        const float sv = silu_f(acc[rb][cb][r] + bS[nl]);
        y[(size_t)(m0 + ml) * DIM + n0 + nl] = Ay * sv;
      }
    }
}

extern "C" void kernel_launch(void* const* d_in, const int* in_sizes, int n_in,
                              void* d_out, int out_size, void* d_ws, size_t ws_size,
                              hipStream_t stream) {
  const float* x      = (const float*)d_in[0];
  const float* hidden = (const float*)d_in[1];
  const float* W_z    = (const float*)d_in[2];
  const float* b_z    = (const float*)d_in[3];
  const float* W_za   = (const float*)d_in[4];
  const float* b_za   = (const float*)d_in[5];
  const float* W_y    = (const float*)d_in[6];
  const float* b_y    = (const float*)d_in[7];
  const float* W_ya   = (const float*)d_in[8];
  const float* b_ya   = (const float*)d_in[9];
  const float* W_dt   = (const float*)d_in[10];
  const float* b_dt   = (const float*)d_in[11];
  const float* ln_a   = (const float*)d_in[12];
  const float* gn_w   = (const float*)d_in[13];
  const float* gn_b   = (const float*)d_in[14];

  char* ws = (char*)d_ws;
  unsigned short* xb   = (unsigned short*)(ws);             // 8,388,608 B
  unsigned short* Wzb  = (unsigned short*)(ws + 8388608);   // 2,097,152 B
  unsigned short* Wzab = (unsigned short*)(ws + 10485760);  // 2,097,152 B
  unsigned short* Wyab = (unsigned short*)(ws + 12582912);  // 2,097,152 B
  float* ln_da  = (float*)(ws + 14680064);                  // 131,072 B
  float* Zs     = (float*)(ws + 14811136);                  // 8,192 B
  float* v      = (float*)(ws + 14819328);                  // 8,192 B
  float* wdiag  = (float*)(ws + 14827520);                  // 8,192 B
  float* stats3 = (float*)(ws + 14835712);                  // 256 B
  float* vtg    = (float*)(ws + 14835968);                  // 8,192 B
  float* wtg    = (float*)(ws + 14844160);                  // 8,192 B
  float* Gv     = (float*)(ws + 14852352);                  // 65,536 B
  float* Gw     = (float*)(ws + 14917888);                  // 65,536 B
  float* constc = (float*)(ws + 14983424);                  // 4,096 B
  float* alpha2 = (float*)(ws + 14987520);                  // 262,144 B

  float* y = (float*)d_out;
  float* hidden_next = y + (size_t)M_TOT * DIM;

  hipMemsetAsync(Zs, 0, BATCH * DIM * sizeof(float), stream);

  cvt_all<<<7168, 256, 0, stream>>>((const float4*)x, (const float4*)W_z,
                                    (const float4*)W_za, (const float4*)W_ya,
                                    (ushort4*)xb, (ushort4*)Wzb,
                                    (ushort4*)Wzab, (ushort4*)Wyab);

  dt_kernel<<<M_TOT, 256, 0, stream>>>(x, W_dt, b_dt, ln_a, ln_da);

  gemm_z<<<dim3(8, 32), 256, 0, stream>>>(xb, Wzb, Wzab, b_z, b_za, Zs, wdiag);

  stats_kernel<<<16, 64, 0, stream>>>(Zs, hidden, wdiag, gn_w, v, vtg, wtg, stats3);
  proj_kernel<<<256, 256, 0, stream>>>(W_y, vtg, wtg, gn_b, b_y, Gv, Gw, constc);
  scan_kernel<<<16, 64, 0, stream>>>(ln_da, stats3, v, wdiag, alpha2, hidden_next);

  gemm_y<<<dim3(8, 32), 256, 0, stream>>>(xb, Wyab, b_ya, alpha2, Gv, Gw, constc, y);
}

// Round 4
// 207.270 us; speedup vs baseline: 2.1799x; 1.0858x over previous
//
#include <hip/hip_runtime.h>
#include <stdint.h>

#define DIM   1024
#define L_SEQ 2048
#define BATCH 2
#define NH    8
#define M_TOT 4096   // BATCH * L_SEQ
#define EPS_F 1e-5f

typedef __bf16 bf16x8 __attribute__((ext_vector_type(8)));
typedef unsigned short u16x8 __attribute__((ext_vector_type(8)));
typedef float f32x4 __attribute__((ext_vector_type(4)));

__device__ __forceinline__ unsigned short f2bf(float f) {
  unsigned int u = __float_as_uint(f);
  u += 0x7FFFu + ((u >> 16) & 1u);   // RNE
  return (unsigned short)(u >> 16);
}

__device__ __forceinline__ f32x4 mfma_bf16(u16x8 a, u16x8 b, f32x4 c) {
  return __builtin_amdgcn_mfma_f32_16x16x32_bf16(
      __builtin_bit_cast(bf16x8, a), __builtin_bit_cast(bf16x8, b), c, 0, 0, 0);
}

__device__ __forceinline__ float silu_f(float v) {
  return v / (1.f + __expf(-v));
}

// async global -> LDS, 16 bytes per lane (global_load_lds_dwordx4)
__device__ __forceinline__ void gload16(const unsigned short* g, unsigned short* l) {
  __builtin_amdgcn_global_load_lds(
      (const __attribute__((address_space(1))) unsigned int*)g,
      (__attribute__((address_space(3))) unsigned int*)l, 16, 0, 0);
}

// ---------------- dt + x->bf16: ln_da = -exp(ln_a)*softplus(x.W_dt[h]+b_dt[h]); xb = bf16(x) ----
__global__ __launch_bounds__(256) void dt_cvt(const float* __restrict__ x,
                                              const float* __restrict__ W_dt,
                                              const float* __restrict__ b_dt,
                                              const float* __restrict__ ln_a,
                                              float* __restrict__ ln_da,
                                              unsigned short* __restrict__ xb) {
  __shared__ float xs[DIM];
  const int row = blockIdx.x;                  // 0..4095
  const int tid = threadIdx.x;
  float4 f = ((const float4*)(x + (size_t)row * DIM))[tid];
  ((float4*)xs)[tid] = f;
  ((ushort4*)(xb + (size_t)row * DIM))[tid] =
      make_ushort4(f2bf(f.x), f2bf(f.y), f2bf(f.z), f2bf(f.w));
  __syncthreads();
  const int wave = tid >> 6, lane = tid & 63;
  for (int h = wave; h < NH; h += 4) {
    const float* w = W_dt + (size_t)h * DIM;
    float s = 0.f;
    for (int k = lane; k < DIM; k += 64) s += xs[k] * w[k];
    for (int off = 32; off > 0; off >>= 1) s += __shfl_down(s, off);
    if (lane == 0) {
      float t = s + b_dt[h];
      float sp = (t > 20.f) ? t : log1pf(expf(t));
      int b = row >> 11, l = row & (L_SEQ - 1);
      ln_da[(size_t)(b * NH + h) * L_SEQ + l] = -expf(ln_a[h]) * sp;
    }
  }
}

// ---------------- weights fp32 -> bf16 ----------------
__global__ __launch_bounds__(256) void cvt_w(const float4* __restrict__ wz,
                                             const float4* __restrict__ wza,
                                             const float4* __restrict__ wya,
                                             ushort4* __restrict__ wzb,
                                             ushort4* __restrict__ wzab,
                                             ushort4* __restrict__ wyab) {
  int i = blockIdx.x * 256 + threadIdx.x;   // 786432 float4s
  const float4* s; ushort4* d; int j;
  if (i < 262144)      { s = wz;  d = wzb;  j = i; }
  else if (i < 524288) { s = wza; d = wzab; j = i - 262144; }
  else                 { s = wya; d = wyab; j = i - 524288; }
  float4 f = s[j];
  d[j] = make_ushort4(f2bf(f.x), f2bf(f.y), f2bf(f.z), f2bf(f.w));
}

// ---- merged GEMM: nt<8: dual z-GEMM (colsum + wdiag); nt>=8: y-GEMM -> Sy=silu(C+b) in d_out ----
// 128x128 tiles, BK=64, global_load_lds(16B) staging, XOR-swizzled LDS chunk placement.
__global__ __launch_bounds__(256) void gemm_all(const unsigned short* __restrict__ xb,
                                                const unsigned short* __restrict__ Wz,
                                                const unsigned short* __restrict__ Wza,
                                                const unsigned short* __restrict__ Wya,
                                                const float* __restrict__ b_z,
                                                const float* __restrict__ b_za,
                                                const float* __restrict__ b_ya,
                                                float* __restrict__ Zs,
                                                float* __restrict__ wdiag,
                                                float* __restrict__ Sy) {
  __shared__ __align__(16) unsigned short As[128 * 64];
  __shared__ __align__(16) unsigned short B0s[128 * 64];
  __shared__ __align__(16) unsigned short B1s[128 * 64];
  __shared__ float colsum[128];

  const int tid = threadIdx.x;
  const int lane = tid & 63, wave = tid >> 6;
  const int wm = wave >> 1, wn = wave & 1;
  const int l16 = lane & 15, quad = lane >> 4;
  const int nt = blockIdx.x, mt = blockIdx.y;
  const bool isZ = (nt < 8);
  const int n0 = (isZ ? nt : nt - 8) * 128;
  const int m0 = mt * 128;

  const unsigned short* srcB0 = isZ ? Wz : Wya;
  const unsigned short* srcB1 = Wza;

  f32x4 acc0[4][4], acc1[4][4];
  const f32x4 zero = {0.f, 0.f, 0.f, 0.f};
  for (int i = 0; i < 4; ++i)
    for (int j = 0; j < 4; ++j) { acc0[i][j] = zero; acc1[i][j] = zero; }

  for (int kt = 0; kt < 16; ++kt) {
    const int k0 = kt * 64;
    __syncthreads();   // previous iteration's ds_reads done; LDS reusable
#pragma unroll
    for (int i = 0; i < 4; ++i) {
      const int s = i * 256 + tid;            // LDS 16B-chunk slot (lane-linear)
      const int row = s >> 3;                 // tile row
      const int kc = (s & 7) ^ (row & 7);     // swizzled k-chunk fetched into this slot
      const size_t gcol = (size_t)(k0 + (kc << 3));
      gload16(xb    + (size_t)(m0 + row) * DIM + gcol, As  + ((size_t)s << 3));
      gload16(srcB0 + (size_t)(n0 + row) * DIM + gcol, B0s + ((size_t)s << 3));
      if (isZ)
        gload16(srcB1 + (size_t)(n0 + row) * DIM + gcol, B1s + ((size_t)s << 3));
    }
    __syncthreads();   // drains vmcnt(0): staged data visible
#pragma unroll
    for (int kk = 0; kk < 2; ++kk) {
      const int kc = kk * 4 + quad;
      u16x8 aF[4], bF0[4], bF1[4];
#pragma unroll
      for (int rb = 0; rb < 4; ++rb) {
        const int r = wm * 64 + rb * 16 + l16;
        aF[rb] = *(const u16x8*)&As[r * 64 + ((kc ^ (r & 7)) << 3)];
      }
#pragma unroll
      for (int cb = 0; cb < 4; ++cb) {
        const int r = wn * 64 + cb * 16 + l16;
        const int off = r * 64 + ((kc ^ (r & 7)) << 3);
        bF0[cb] = *(const u16x8*)&B0s[off];
        if (isZ) bF1[cb] = *(const u16x8*)&B1s[off];
      }
#pragma unroll
      for (int rb = 0; rb < 4; ++rb)
#pragma unroll
        for (int cb = 0; cb < 4; ++cb) {
          acc0[rb][cb] = mfma_bf16(aF[rb], bF0[cb], acc0[rb][cb]);
          if (isZ) acc1[rb][cb] = mfma_bf16(aF[rb], bF1[cb], acc1[rb][cb]);
        }
    }
  }

  if (isZ) {
    // U = acc0 + b_z, V = acc1 + b_za; strict-lower colsum -> Zs; diagonal (l==h) -> wdiag
    __syncthreads();
    if (tid < 128) colsum[tid] = 0.f;
    __syncthreads();
    const int b = m0 >> 11;
    const int h = nt;
#pragma unroll
    for (int cb = 0; cb < 4; ++cb) {
      const int nl = wn * 64 + cb * 16 + l16;
      const int n = n0 + nl;
      const float bz = b_z[n], ba = b_za[n];
      float ssum = 0.f;
#pragma unroll
      for (int rb = 0; rb < 4; ++rb) {
        const int mlb = wm * 64 + rb * 16 + quad * 4;
#pragma unroll
        for (int r = 0; r < 4; ++r) {
          const int l = (m0 + mlb + r) & (L_SEQ - 1);
          float u  = acc0[rb][cb][r] + bz;
          float vv = acc1[rb][cb][r] + ba;
          if (l > h) ssum += u * silu_f(vv);
          else if (l == h)
            wdiag[(size_t)(b * NH + h) * 128 + nl] = u * silu_f(vv);
        }
      }
      atomicAdd(&colsum[nl], ssum);
    }
    __syncthreads();
    if (tid < 128) atomicAdd(&Zs[(size_t)b * DIM + n0 + tid], colsum[tid]);
  } else {
    // Sy = silu(acc0 + b_ya), stored fp32 in-place in d_out's y region
#pragma unroll
    for (int cb = 0; cb < 4; ++cb) {
      const int nl = wn * 64 + cb * 16 + l16;
      const float bb = b_ya[n0 + nl];
#pragma unroll
      for (int rb = 0; rb < 4; ++rb) {
        const int mlb = wm * 64 + rb * 16 + quad * 4;
#pragma unroll
        for (int r = 0; r < 4; ++r)
          Sy[(size_t)(m0 + mlb + r) * DIM + n0 + nl] = silu_f(acc0[rb][cb][r] + bb);
      }
    }
  }
}

// ---- per (b,h): v = Zs+hidden; stats; vtg/wtg; then scan -> alpha2; hidden_next ----
__global__ __launch_bounds__(64) void stats_scan(const float* __restrict__ Zs,
                                                 const float* __restrict__ hidden,
                                                 const float* __restrict__ wdiag,
                                                 const float* __restrict__ gn_w,
                                                 const float* __restrict__ ln_da,
                                                 float* __restrict__ vtg,
                                                 float* __restrict__ wtg,
                                                 float* __restrict__ alpha2,
                                                 float* __restrict__ hidden_next) {
  const int bh = blockIdx.x, b = bh >> 3, h = bh & 7;
  const int lane = threadIdx.x;
  const size_t base = (size_t)bh * 128;
  const float v0 = Zs[(size_t)b * DIM + h * 128 + lane]      + hidden[base + lane];
  const float v1 = Zs[(size_t)b * DIM + h * 128 + 64 + lane] + hidden[base + 64 + lane];
  const float w0 = wdiag[base + lane];
  const float w1 = wdiag[base + 64 + lane];

  float sv = v0 + v1, sw = w0 + w1;
  for (int off = 32; off > 0; off >>= 1) {
    sv += __shfl_down(sv, off);
    sw += __shfl_down(sw, off);
  }
  const float muv = __shfl(sv, 0) * (1.f / 128.f);
  const float muw = __shfl(sw, 0) * (1.f / 128.f);

  const float a0 = v0 - muv, a1 = v1 - muv;
  const float c0 = w0 - muw, c1 = w1 - muw;
  float rvv = a0 * a0 + a1 * a1;
  float rvw = a0 * c0 + a1 * c1;
  float rww = c0 * c0 + c1 * c1;
  for (int off = 32; off > 0; off >>= 1) {
    rvv += __shfl_down(rvv, off);
    rvw += __shfl_down(rvw, off);
    rww += __shfl_down(rww, off);
  }
  const float svv = __shfl(rvv, 0) * (1.f / 128.f);
  const float svw = __shfl(rvw, 0) * (1.f / 128.f);
  const float sww = __shfl(rww, 0) * (1.f / 128.f);

  const float gw = gn_w[h];
  vtg[base + lane] = a0 * gw;  vtg[base + 64 + lane] = a1 * gw;
  wtg[base + lane] = c0 * gw;  wtg[base + 64 + lane] = c1 * gw;

  // scan: S = cumsum(ln_da); c = exp(S); D = rsqrt(c^2*svv + 2c*svw + sww + eps)
  const float* src = ln_da + (size_t)bh * L_SEQ;
  float carry = 0.f;
  for (int c = 0; c < L_SEQ / 64; ++c) {
    float val = src[c * 64 + lane];
#pragma unroll
    for (int off = 1; off < 64; off <<= 1) {
      float nv = __shfl_up(val, off);
      if (lane >= off) val += nv;
    }
    const float S = carry + val;
    const float ce = expf(S);
    const float D = rsqrtf(ce * ce * svv + 2.f * ce * svw + sww + EPS_F);
    const int l = c * 64 + lane;
    float* ap = alpha2 + ((size_t)(b * L_SEQ + l) * NH + h) * 2;
    ap[0] = ce * D;
    ap[1] = D;
    carry += __shfl(val, 63);
  }
  const float clast = expf(carry);
  hidden_next[base + lane]      = clast * v0 + w0;
  hidden_next[base + 64 + lane] = clast * v1 + w1;
}

// ---- per row n of W_y: Gv[bh][n], Gw[bh][n] (all 16 bh) and constc[n] ----
__global__ __launch_bounds__(256) void proj_kernel(const float* __restrict__ W_y,
                                                   const float* __restrict__ vtg,
                                                   const float* __restrict__ wtg,
                                                   const float* __restrict__ gn_b,
                                                   const float* __restrict__ b_y,
                                                   float* __restrict__ Gv,
                                                   float* __restrict__ Gw,
                                                   float* __restrict__ constc) {
  const int tid = threadIdx.x, wave = tid >> 6, lane = tid & 63;
  const int n = blockIdx.x * 4 + wave;
  const float4* row = (const float4*)(W_y + (size_t)n * DIM);
  const int half = lane >> 5, l32 = lane & 31;
  float cc = 0.f;
#pragma unroll
  for (int p = 0; p < 4; ++p) {
    const int h = p * 2 + half;
    float4 wv = row[p * 64 + lane];
    const float4 va = *(const float4*)&vtg[(size_t)h * 128 + l32 * 4];
    const float4 vb = *(const float4*)&vtg[(size_t)(8 + h) * 128 + l32 * 4];
    const float4 wa = *(const float4*)&wtg[(size_t)h * 128 + l32 * 4];
    const float4 wb = *(const float4*)&wtg[(size_t)(8 + h) * 128 + l32 * 4];
    float gv0 = wv.x * va.x + wv.y * va.y + wv.z * va.z + wv.w * va.w;
    float gv1 = wv.x * vb.x + wv.y * vb.y + wv.z * vb.z + wv.w * vb.w;
    float gw0 = wv.x * wa.x + wv.y * wa.y + wv.z * wa.z + wv.w * wa.w;
    float gw1 = wv.x * wb.x + wv.y * wb.y + wv.z * wb.z + wv.w * wb.w;
    cc += (wv.x + wv.y + wv.z + wv.w) * gn_b[h];
#pragma unroll
    for (int off = 16; off > 0; off >>= 1) {
      gv0 += __shfl_down(gv0, off, 32);
      gv1 += __shfl_down(gv1, off, 32);
      gw0 += __shfl_down(gw0, off, 32);
      gw1 += __shfl_down(gw1, off, 32);
    }
    if (l32 == 0) {
      Gv[(size_t)h * DIM + n]       = gv0;
      Gv[(size_t)(8 + h) * DIM + n] = gv1;
      Gw[(size_t)h * DIM + n]       = gw0;
      Gw[(size_t)(8 + h) * DIM + n] = gw1;
    }
  }
  for (int off = 32; off > 0; off >>= 1) cc += __shfl_down(cc, off);
  if (lane == 0) constc[n] = b_y[n] + cc;
}

// ---- finalize: y[m,n] = (constc[n] + sum_k alpha2[m,k]*G[k,n]) * Sy[m,n], in place ----
__global__ __launch_bounds__(256) void finalize(const float* __restrict__ alpha2,
                                                const float* __restrict__ Gv,
                                                const float* __restrict__ Gw,
                                                const float* __restrict__ constc,
                                                float* __restrict__ y) {
  const int tid = threadIdx.x;
  const int n0 = blockIdx.x * 256;
  const int m0 = blockIdx.y * 64;
  const int b = m0 >> 11;
  __shared__ float aS[64 * 16];
  ((float4*)aS)[tid] = ((const float4*)(alpha2 + (size_t)m0 * 16))[tid];
  __syncthreads();
  const int c = tid & 63;     // col4 within n-tile
  const int rg = tid >> 6;    // row group (16 rows each)
  const int n = n0 + c * 4;
  f32x4 g[16 * 2];
#pragma unroll
  for (int h = 0; h < 8; ++h) {
    g[2 * h]     = *(const f32x4*)&Gv[(size_t)(b * NH + h) * DIM + n];
    g[2 * h + 1] = *(const f32x4*)&Gw[(size_t)(b * NH + h) * DIM + n];
  }
  const f32x4 cc = *(const f32x4*)&constc[n];
#pragma unroll
  for (int j = 0; j < 16; ++j) {
    const int m = m0 + rg * 16 + j;
    const float* a = &aS[(rg * 16 + j) * 16];
    f32x4 Ay = cc;
#pragma unroll
    for (int k = 0; k < 16; ++k) Ay += a[k] * g[k];
    f32x4 s = *(const f32x4*)&y[(size_t)m * DIM + n];
    *(f32x4*)&y[(size_t)m * DIM + n] = Ay * s;
  }
}

extern "C" void kernel_launch(void* const* d_in, const int* in_sizes, int n_in,
                              void* d_out, int out_size, void* d_ws, size_t ws_size,
                              hipStream_t stream) {
  const float* x      = (const float*)d_in[0];
  const float* hidden = (const float*)d_in[1];
  const float* W_z    = (const float*)d_in[2];
  const float* b_z    = (const float*)d_in[3];
  const float* W_za   = (const float*)d_in[4];
  const float* b_za   = (const float*)d_in[5];
  const float* W_y    = (const float*)d_in[6];
  const float* b_y    = (const float*)d_in[7];
  const float* W_ya   = (const float*)d_in[8];
  const float* b_ya   = (const float*)d_in[9];
  const float* W_dt   = (const float*)d_in[10];
  const float* b_dt   = (const float*)d_in[11];
  const float* ln_a   = (const float*)d_in[12];
  const float* gn_w   = (const float*)d_in[13];
  const float* gn_b   = (const float*)d_in[14];

  char* ws = (char*)d_ws;
  unsigned short* xb   = (unsigned short*)(ws);             // 8,388,608 B
  unsigned short* Wzb  = (unsigned short*)(ws + 8388608);   // 2,097,152 B
  unsigned short* Wzab = (unsigned short*)(ws + 10485760);  // 2,097,152 B
  unsigned short* Wyab = (unsigned short*)(ws + 12582912);  // 2,097,152 B
  float* ln_da  = (float*)(ws + 14680064);                  // 131,072 B
  float* Zs     = (float*)(ws + 14811136);                  // 8,192 B
  float* wdiag  = (float*)(ws + 14819328);                  // 8,192 B
  float* vtg    = (float*)(ws + 14827520);                  // 8,192 B
  float* wtg    = (float*)(ws + 14835712);                  // 8,192 B
  float* Gv     = (float*)(ws + 14843904);                  // 65,536 B
  float* Gw     = (float*)(ws + 14909440);                  // 65,536 B
  float* constc = (float*)(ws + 14974976);                  // 4,096 B
  float* alpha2 = (float*)(ws + 14979072);                  // 262,144 B

  float* y = (float*)d_out;
  float* hidden_next = y + (size_t)M_TOT * DIM;

  hipMemsetAsync(Zs, 0, BATCH * DIM * sizeof(float), stream);

  dt_cvt<<<M_TOT, 256, 0, stream>>>(x, W_dt, b_dt, ln_a, ln_da, xb);
  cvt_w<<<3072, 256, 0, stream>>>((const float4*)W_z, (const float4*)W_za,
                                  (const float4*)W_ya,
                                  (ushort4*)Wzb, (ushort4*)Wzab, (ushort4*)Wyab);

  gemm_all<<<dim3(16, 32), 256, 0, stream>>>(xb, Wzb, Wzab, Wyab,
                                             b_z, b_za, b_ya, Zs, wdiag, y);

  stats_scan<<<16, 64, 0, stream>>>(Zs, hidden, wdiag, gn_w, ln_da,
                                    vtg, wtg, alpha2, hidden_next);
  proj_kernel<<<256, 256, 0, stream>>>(W_y, vtg, wtg, gn_b, b_y, Gv, Gw, constc);

  finalize<<<dim3(4, 64), 256, 0, stream>>>(alpha2, Gv, Gw, constc, y);
}